// Round 4
// baseline (1808.978 us; speedup 1.0000x reference)
//
#include <hip/hip_runtime.h>

// ---------------------------------------------------------------------------
// Fused attention block, bf16 MFMA pipeline.
// B=4, L=2048, HID=2048, H=16, DH=128, QKV=6144.
// R4: fa Ps halved (48 KB LDS -> 3 blocks/CU, __launch_bounds__(512,6));
// V-transpose fused into GEMM1 epilogue (transpose_v kernel + Vb removed);
// rmsnorm_rope launches merged.  GEMM swizzle kept (R3: 0 bank conflicts).
// ---------------------------------------------------------------------------

typedef __attribute__((ext_vector_type(8))) short bf16x8;   // 8 bf16 = 4 VGPRs
typedef __attribute__((ext_vector_type(4))) float f32x4;
typedef __attribute__((ext_vector_type(4))) unsigned short us4;

#if __has_builtin(__builtin_amdgcn_exp2f)
#define EXP2(x) __builtin_amdgcn_exp2f(x)
#else
#define EXP2(x) exp2f(x)
#endif

__device__ __forceinline__ unsigned short f2bf(float f) {
    unsigned int x = __float_as_uint(f);
    unsigned int r = x + 0x7fffu + ((x >> 16) & 1u);   // RN-even
    return (unsigned short)(r >> 16);
}
__device__ __forceinline__ unsigned short f2bf_fast(float f) {   // round-half-up
    return (unsigned short)((__float_as_uint(f) + 0x8000u) >> 16);
}
__device__ __forceinline__ float bf2f(unsigned short u) {
    return __uint_as_float(((unsigned int)u) << 16);
}

// async global->LDS, 16 B per lane; LDS dest = wave-uniform base + lane*16
__device__ __forceinline__ void gll16(const unsigned short* g, unsigned short* l) {
    __builtin_amdgcn_global_load_lds(
        (const __attribute__((address_space(1))) unsigned int*)g,
        (__attribute__((address_space(3))) unsigned int*)l, 16, 0, 0);
}

// ---------------------------------------------------------------------------
// elementwise fp32 -> bf16 (vectorized float4 -> ushort4)
// ---------------------------------------------------------------------------
__global__ __launch_bounds__(256) void cvt_bf16(const float* __restrict__ in,
                                                unsigned short* __restrict__ out) {
    int i = blockIdx.x * 256 + threadIdx.x;       // over n/4
    float4 v = ((const float4*)in)[i];
    us4 r;
    r[0] = f2bf(v.x); r[1] = f2bf(v.y); r[2] = f2bf(v.z); r[3] = f2bf(v.w);
    ((us4*)out)[i] = r;
}

// ---------------------------------------------------------------------------
// fp32 (R x C) -> bf16 transposed (C x R).  block (32,8), 32x32 LDS tile.
// ---------------------------------------------------------------------------
__global__ __launch_bounds__(256) void transpose_cvt(const float* __restrict__ in,
                                                     unsigned short* __restrict__ out,
                                                     int R, int C) {
    __shared__ float t[32][33];
    int c0 = blockIdx.x * 32, r0 = blockIdx.y * 32;
    int tx = threadIdx.x, ty = threadIdx.y;
#pragma unroll
    for (int i = 0; i < 4; i++)
        t[ty + i * 8][tx] = in[(size_t)(r0 + ty + i * 8) * C + c0 + tx];
    __syncthreads();
#pragma unroll
    for (int i = 0; i < 4; i++)
        out[(size_t)(c0 + ty + i * 8) * R + r0 + tx] = f2bf(t[tx][ty + i * 8]);
}

// ---------------------------------------------------------------------------
// shared GEMM mainloop: C[128m x 128n] += A(M,K) * Bt(N,K)^T, bf16, BK=64.
// 256 threads = 4 waves (2x2), each wave 64x64 = 4x4 frags of 16x16x32 MFMA.
// LDS rows (64 elems = 8 chunks of 16B) XOR-swizzled: chunk ^= row&7.
// R3 measured: 0 bank conflicts with this pattern.
// ---------------------------------------------------------------------------
__device__ __forceinline__ void gemm_core(const unsigned short* __restrict__ A,
                                          const unsigned short* __restrict__ Bt,
                                          int K, int rowA0, int colB0,
                                          unsigned short* As, unsigned short* Bs,
                                          f32x4 acc[4][4]) {
    const int tid = threadIdx.x;
    const int w = tid >> 6, lane = tid & 63;
    const int quad = lane >> 4, l15 = lane & 15;
    const int wm = w >> 1, wn = w & 1;
    const int lr = lane >> 3;                 // row within the 8-row chunk
    const int lc = ((lane & 7) ^ lr) * 8;     // swizzled element col within 64

    const unsigned short* ga[4]; const unsigned short* gb[4];
    unsigned short* la[4]; unsigned short* lb[4];
#pragma unroll
    for (int i = 0; i < 4; i++) {
        int r = w * 32 + i * 8;
        ga[i] = A  + (size_t)(rowA0 + r + lr) * K + lc;
        gb[i] = Bt + (size_t)(colB0 + r + lr) * K + lc;
        la[i] = As + r * 64;
        lb[i] = Bs + r * 64;
    }
    const int sw = (l15 & 7);                 // read-side swizzle key
    const int KT = K >> 6;
    for (int kt = 0; kt < KT; kt++) {
        const int ko = kt * 64;
#pragma unroll
        for (int i = 0; i < 4; i++) gll16(ga[i] + ko, la[i]);
#pragma unroll
        for (int i = 0; i < 4; i++) gll16(gb[i] + ko, lb[i]);
        __syncthreads();
#pragma unroll
        for (int kk = 0; kk < 2; kk++) {
            bf16x8 af[4], bfr[4];
#pragma unroll
            for (int mi = 0; mi < 4; mi++)
                af[mi] = *(const bf16x8*)&As[(wm * 64 + mi * 16 + l15) * 64 +
                                             (((kk * 4 + quad) ^ sw) * 8)];
#pragma unroll
            for (int ni = 0; ni < 4; ni++)
                bfr[ni] = *(const bf16x8*)&Bs[(wn * 64 + ni * 16 + l15) * 64 +
                                              (((kk * 4 + quad) ^ sw) * 8)];
#pragma unroll
            for (int mi = 0; mi < 4; mi++)
#pragma unroll
                for (int ni = 0; ni < 4; ni++)
                    acc[mi][ni] = __builtin_amdgcn_mfma_f32_16x16x32_bf16(
                        af[mi], bfr[ni], acc[mi][ni], 0, 0, 0);
        }
        __syncthreads();
    }
}

// ---------------------------------------------------------------------------
// GEMM1: proj = Xb @ Wqkvg.  Epilogue: q/k scatter -> (b,h,l,d); V written
// TRANSPOSED -> Vt (b,h,d,l) via LDS tile (fused transpose_v); gate -> sigmoid.
// ---------------------------------------------------------------------------
__global__ __launch_bounds__(256) void gemm_qkvg(const unsigned short* __restrict__ A,
                                                 const unsigned short* __restrict__ Bt,
                                                 unsigned short* __restrict__ Qb,
                                                 unsigned short* __restrict__ Kb,
                                                 unsigned short* __restrict__ Vt,
                                                 unsigned short* __restrict__ Gb) {
    __shared__ unsigned short smem[128 * 128];   // As|Bs in core, vtile in epilogue
    unsigned short* As = smem;
    unsigned short* Bs = smem + 128 * 64;
    f32x4 acc[4][4];
    f32x4 z = {0.f, 0.f, 0.f, 0.f};
#pragma unroll
    for (int i = 0; i < 4; i++)
#pragma unroll
        for (int j = 0; j < 4; j++) acc[i][j] = z;

    const int rowA0 = blockIdx.y * 128, colB0 = blockIdx.x * 128;
    gemm_core(A, Bt, 2048, rowA0, colB0, As, Bs, acc);

    const int tid = threadIdx.x, w = tid >> 6, lane = tid & 63;
    const int quad = lane >> 4, l15 = lane & 15;
    const int wm = w >> 1, wn = w & 1;
    const int sec = blockIdx.x >> 4;     // 0=q 1=k 2=v 3=gate
    const int h = blockIdx.x & 15;

    if (sec == 2) {
        // V: acc -> LDS as (d, l) tile, 16B-chunk swizzled (chunk ^= d&15)
#pragma unroll
        for (int mi = 0; mi < 4; mi++)
#pragma unroll
            for (int ni = 0; ni < 4; ni++)
#pragma unroll
                for (int i = 0; i < 4; i++) {
                    int ll = wm * 64 + mi * 16 + quad * 4 + i;   // l within tile
                    int d  = wn * 64 + ni * 16 + l15;
                    smem[d * 128 + (((ll >> 3) ^ (d & 15)) * 8) + (ll & 7)] =
                        f2bf(acc[mi][ni][i]);
                }
        __syncthreads();
        const int b_ = rowA0 >> 11, l0 = rowA0 & 2047;
        const int r = tid >> 1, hf = tid & 1;    // r = d row, hf = 64-col half
        unsigned short* drow = Vt + (size_t)(b_ * 16 + h) * 128 * 2048 +
                               (size_t)r * 2048 + l0;
#pragma unroll
        for (int jj = 0; jj < 8; jj++) {
            int jcol = hf * 8 + jj;
            *(bf16x8*)(drow + jcol * 8) =
                *(const bf16x8*)&smem[r * 128 + ((jcol ^ (r & 15)) * 8)];
        }
    } else if (sec == 3) {
#pragma unroll
        for (int mi = 0; mi < 4; mi++)
#pragma unroll
            for (int ni = 0; ni < 4; ni++)
#pragma unroll
                for (int i = 0; i < 4; i++) {
                    int rowg = rowA0 + wm * 64 + mi * 16 + quad * 4 + i;  // b*L+l
                    int d = wn * 64 + ni * 16 + l15;
                    float g = 1.f / (1.f + __expf(-acc[mi][ni][i]));
                    Gb[((size_t)rowg << 11) + h * 128 + d] = f2bf(g);
                }
    } else {
        unsigned short* dst = (sec == 0) ? Qb : Kb;
#pragma unroll
        for (int mi = 0; mi < 4; mi++)
#pragma unroll
            for (int ni = 0; ni < 4; ni++)
#pragma unroll
                for (int i = 0; i < 4; i++) {
                    int rowg = rowA0 + wm * 64 + mi * 16 + quad * 4 + i;
                    int d = wn * 64 + ni * 16 + l15;
                    int b_ = rowg >> 11, l_ = rowg & 2047;
                    dst[(((size_t)(b_ * 16 + h) * 2048 + l_) << 7) + d] =
                        f2bf(acc[mi][ni][i]);
                }
    }
}

// ---------------------------------------------------------------------------
// GEMM2: out = OG @ Wout  (fp32 epilogue straight to d_out)
// ---------------------------------------------------------------------------
__global__ __launch_bounds__(256) void gemm_out(const unsigned short* __restrict__ A,
                                                const unsigned short* __restrict__ Bt,
                                                float* __restrict__ C) {
    __shared__ unsigned short As[128 * 64], Bs[128 * 64];
    f32x4 acc[4][4];
    f32x4 z = {0.f, 0.f, 0.f, 0.f};
#pragma unroll
    for (int i = 0; i < 4; i++)
#pragma unroll
        for (int j = 0; j < 4; j++) acc[i][j] = z;

    const int rowA0 = blockIdx.y * 128, colB0 = blockIdx.x * 128;
    gemm_core(A, Bt, 2048, rowA0, colB0, As, Bs, acc);

    const int tid = threadIdx.x, w = tid >> 6, lane = tid & 63;
    const int quad = lane >> 4, l15 = lane & 15;
    const int wm = w >> 1, wn = w & 1;
#pragma unroll
    for (int mi = 0; mi < 4; mi++)
#pragma unroll
        for (int ni = 0; ni < 4; ni++)
#pragma unroll
            for (int i = 0; i < 4; i++) {
                int rowg = rowA0 + wm * 64 + mi * 16 + quad * 4 + i;
                int col = colB0 + wn * 64 + ni * 16 + l15;
                C[(size_t)rowg * 2048 + col] = acc[mi][ni][i];
            }
}

// ---------------------------------------------------------------------------
// RMSNorm + RoPE in place on Q and K (each (64, 2048, 128) bf16), one launch.
// blockIdx.y picks the tensor; one wave per row.
// ---------------------------------------------------------------------------
__global__ __launch_bounds__(256) void rmsnorm_rope(unsigned short* __restrict__ Qp,
                                                    unsigned short* __restrict__ Kp) {
    unsigned short* X = blockIdx.y ? Kp : Qp;
    const int tid = threadIdx.x;
    const int row = blockIdx.x * 4 + (tid >> 6);
    const int lane = tid & 63;
    unsigned short* p = X + (size_t)row * 128;
    const int l_ = row & 2047;                      // sequence position
    float x1 = bf2f(p[lane]);
    float x2 = bf2f(p[lane + 64]);
    float ss = x1 * x1 + x2 * x2;
#pragma unroll
    for (int off = 32; off >= 1; off >>= 1) ss += __shfl_xor(ss, off, 64);
    float r = rsqrtf(ss * (1.f / 128.f) + 1e-5f);
    x1 *= r; x2 *= r;
    float inv = exp2f(-(float)lane * (13.287712379549449f / 64.f));
    float ang = (float)l_ * inv;
    float sn, cs;
    sincosf(ang, &sn, &cs);
    p[lane]      = f2bf(x1 * cs - x2 * sn);
    p[lane + 64] = f2bf(x1 * sn + x2 * cs);
}

// ---------------------------------------------------------------------------
// Flash attention (causal) + gate fusion, no-max softmax.  R4 shape:
// grid 512 blocks, 512 threads = 8 waves; q-tile 256 (wave w owns q rows
// [w*32, w*32+32)); KV tile 64, PV in two 32-kv halves so Ps is 16 KB.
// LDS: Ks 16K + Vs 16K + Ps 16K = 48 KB -> 3 blocks/CU (launch_bounds(512,6)).
// Block mapping groups all 8 q-chunks of a head on one XCD.
// P is wave-local: no barrier between P write and PV read.
// ---------------------------------------------------------------------------
__global__ __launch_bounds__(512, 6) void fa_kernel(const unsigned short* __restrict__ Q,
                                                    const unsigned short* __restrict__ K,
                                                    const unsigned short* __restrict__ Vt,
                                                    const unsigned short* __restrict__ G,
                                                    unsigned short* __restrict__ Og) {
    __shared__ unsigned short Ks[64 * 128];     // (kv, d)
    __shared__ unsigned short Vs[128 * 64];     // (d, kv)
    __shared__ unsigned short Ps[256 * 32];     // (q, kv-half) wave-local slabs
    const int g = blockIdx.x;
    const int bh = (g & 7) | ((g >> 6) << 3);   // all qc of a head share g%8
    const int qc = (g >> 3) & 7;                // q-chunk 0..7 (256 rows each)
    const int tid = threadIdx.x, w = tid >> 6, lane = tid & 63;
    const int quad = lane >> 4, l15 = lane & 15;
    const int sw = l15 & 7;
    const int qrow0 = qc * 256 + w * 32;        // global q row base for this wave
    const float CS = 0.12751740395609812f;      // (1/sqrt(128)) * log2(e)

    // Q fragments (A-operand layout), loaded once
    bf16x8 qf[2][4];
#pragma unroll
    for (int mi = 0; mi < 2; mi++)
#pragma unroll
        for (int kt = 0; kt < 4; kt++)
            qf[mi][kt] = *(const bf16x8*)(Q + ((size_t)bh * 2048 + qrow0 + mi * 16 + l15) * 128
                                             + kt * 32 + quad * 8);

    f32x4 o[2][8];
    f32x4 z = {0.f, 0.f, 0.f, 0.f};
#pragma unroll
    for (int mi = 0; mi < 2; mi++)
#pragma unroll
        for (int nj = 0; nj < 8; nj++) o[mi][nj] = z;
    float rowsum[2][4];
#pragma unroll
    for (int mi = 0; mi < 2; mi++)
#pragma unroll
        for (int i = 0; i < 4; i++) rowsum[mi][i] = 0.f;

    const unsigned short* Kbase = K + (size_t)bh * 2048 * 128;
    const unsigned short* Vtb   = Vt + (size_t)bh * 128 * 2048;

    // Ps a-frag read offsets (row-dependent swizzle key = (row>>1)&3)
    const int pr0 = w * 32 + l15, pr1 = pr0 + 16;
    const int pk0 = (pr0 >> 1) & 3, pk1 = (pr1 >> 1) & 3;

    const int NJ = 4 * (qc + 1);    // kv tiles of 64
    for (int j = 0; j < NJ; j++) {
        __syncthreads();   // prev iter's Ks/Vs reads complete

        // --- stage K tile: 64 rows x 256 B; wave w -> rows [w*8, w*8+8) ---
        {
            const int rowoff = lane >> 4, c = lane & 15;
#pragma unroll
            for (int i = 0; i < 2; i++) {
                int r0 = w * 8 + i * 4;
                int row = r0 + rowoff;
                int cs_ = (c & 8) | ((c & 7) ^ (row & 7));
                gll16(Kbase + (size_t)(j * 64 + row) * 128 + cs_ * 8, Ks + r0 * 128);
            }
        }
        // --- stage V tile: 128 d-rows x 128 B; wave w -> rows [w*16, w*16+16) ---
        {
            const int rowoff = lane >> 3, c = lane & 7;
#pragma unroll
            for (int i = 0; i < 2; i++) {
                int r0 = w * 16 + i * 8;
                int row = r0 + rowoff;
                gll16(Vtb + (size_t)row * 2048 + j * 64 + ((c ^ (row & 7)) * 8),
                      Vs + r0 * 64);
            }
        }
        __syncthreads();   // staged data visible

        if (j * 64 >= qrow0 + 32) continue;   // tile fully masked for this wave

        // --- S = Q K^T (raw logits) ---
        f32x4 s[2][4];
#pragma unroll
        for (int mi = 0; mi < 2; mi++)
#pragma unroll
            for (int nj = 0; nj < 4; nj++) s[mi][nj] = z;
#pragma unroll
        for (int kt = 0; kt < 4; kt++)
#pragma unroll
            for (int nj = 0; nj < 4; nj++) {
                bf16x8 bfr = *(const bf16x8*)&Ks[(nj * 16 + l15) * 128 +
                                                 (((kt * 4 + quad) ^ sw) * 8)];
                s[0][nj] = __builtin_amdgcn_mfma_f32_16x16x32_bf16(qf[0][kt], bfr, s[0][nj], 0, 0, 0);
                s[1][nj] = __builtin_amdgcn_mfma_f32_16x16x32_bf16(qf[1][kt], bfr, s[1][nj], 0, 0, 0);
            }

        // --- two 32-kv halves: exp + P write + PV MFMA (Ps wave-local) ---
        const bool diag = (j * 64 + 63 > qrow0);   // any masking in this tile?
#pragma unroll
        for (int hh = 0; hh < 2; hh++) {
#pragma unroll
            for (int mi = 0; mi < 2; mi++)
#pragma unroll
                for (int njh = 0; njh < 2; njh++) {
                    const int nj = hh * 2 + njh;
#pragma unroll
                    for (int i = 0; i < 4; i++) {
                        float pp = EXP2(s[mi][nj][i] * CS);
                        int row_l = mi * 16 + quad * 4 + i;      // 0..31 in slab
                        if (diag) {
                            int col_g = j * 64 + nj * 16 + l15;
                            if (col_g > qrow0 + row_l) pp = 0.f;
                        }
                        rowsum[mi][i] += pp;
                        int row = w * 32 + row_l;
                        int kv = njh * 16 + l15;                 // 0..31
                        Ps[row * 32 + ((((kv >> 3) ^ ((row >> 1) & 3)) * 8)) + (kv & 7)] =
                            f2bf_fast(pp);
                    }
                }
            // PV for this half (K=32 -> one MFMA pair per o-column)
            bf16x8 a0 = *(const bf16x8*)&Ps[pr0 * 32 + ((quad ^ pk0) * 8)];
            bf16x8 a1 = *(const bf16x8*)&Ps[pr1 * 32 + ((quad ^ pk1) * 8)];
#pragma unroll
            for (int nj = 0; nj < 8; nj++) {
                bf16x8 bfr = *(const bf16x8*)&Vs[(nj * 16 + l15) * 64 +
                                                 (((hh * 4 + quad) ^ sw) * 8)];
                o[0][nj] = __builtin_amdgcn_mfma_f32_16x16x32_bf16(a0, bfr, o[0][nj], 0, 0, 0);
                o[1][nj] = __builtin_amdgcn_mfma_f32_16x16x32_bf16(a1, bfr, o[1][nj], 0, 0, 0);
            }
        }
    }

    // --- epilogue: reduce rowsum across l15 lanes, O/l * gate -> Og ---
    const int b_ = bh >> 4, h = bh & 15;
#pragma unroll
    for (int mi = 0; mi < 2; mi++)
#pragma unroll
        for (int i = 0; i < 4; i++) {
            float t = rowsum[mi][i];
#pragma unroll
            for (int off = 1; off < 16; off <<= 1) t += __shfl_xor(t, off, 16);
            float rl = 1.f / t;
            int l_ = qrow0 + mi * 16 + quad * 4 + i;
#pragma unroll
            for (int nj = 0; nj < 8; nj++) {
                int d = nj * 16 + l15;
                size_t gi = ((size_t)(b_ * 2048 + l_) * 2048) + h * 128 + d;
                Og[gi] = f2bf(o[mi][nj][i] * rl * bf2f(G[gi]));
            }
        }
}

// ---------------------------------------------------------------------------
// launch
// ---------------------------------------------------------------------------
extern "C" void kernel_launch(void* const* d_in, const int* in_sizes, int n_in,
                              void* d_out, int out_size, void* d_ws, size_t ws_size,
                              hipStream_t stream) {
    const float* X  = (const float*)d_in[0];   // (4,2048,2048)
    const float* Wq = (const float*)d_in[1];   // (2048,8192)
    const float* Wo = (const float*)d_in[2];   // (2048,2048)
    float* out = (float*)d_out;                // (4,2048,2048) fp32

    char* ws = (char*)d_ws;
    const size_t SZ = 33554432ull;             // 16.8M bf16
    unsigned short* Xb  = (unsigned short*)(ws);                 // X bf16 / later OG
    unsigned short* Wqt = (unsigned short*)(ws + SZ);            // Wqkvg^T
    unsigned short* Wot = (unsigned short*)(ws + 2 * SZ);        // 8.4 MB
    unsigned short* Qb  = (unsigned short*)(ws + 2 * SZ + 8388608ull);
    unsigned short* Kb  = (unsigned short*)(ws + 3 * SZ + 8388608ull);
    unsigned short* Vt  = (unsigned short*)(ws + 4 * SZ + 8388608ull);  // (bh,d,l)
    unsigned short* Gb  = (unsigned short*)(ws + 5 * SZ + 8388608ull);
    unsigned short* OG  = Xb;    // reuse: Xb dead after GEMM1

    cvt_bf16<<<16384, 256, 0, stream>>>(X, Xb);
    transpose_cvt<<<dim3(256, 64), dim3(32, 8), 0, stream>>>(Wq, Wqt, 2048, 8192);
    transpose_cvt<<<dim3(64, 64),  dim3(32, 8), 0, stream>>>(Wo, Wot, 2048, 2048);

    gemm_qkvg<<<dim3(64, 64), 256, 0, stream>>>(Xb, Wqt, Qb, Kb, Vt, Gb);

    rmsnorm_rope<<<dim3(32768, 2), 256, 0, stream>>>(Qb, Kb);

    fa_kernel<<<512, 512, 0, stream>>>(Qb, Kb, Vt, Gb, OG);

    gemm_out<<<dim3(16, 64), 256, 0, stream>>>(OG, Wot, out);
}

// Round 5
// 773.382 us; speedup vs baseline: 2.3390x; 2.3390x over previous
//
#include <hip/hip_runtime.h>

// ---------------------------------------------------------------------------
// Fused attention block, bf16 MFMA pipeline.
// B=4, L=2048, HID=2048, H=16, DH=128, QKV=6144.
// R5: fa uses plain __launch_bounds__(512) — R4's (512,6) capped VGPR at ~85
// and spilled the O accumulators (VGPR_Count=40, WRITE_SIZE 2 GB, 1188 us).
// Keep R4's structural wins: Ps 16 KB (48 KB LDS), fused V-transpose in
// GEMM1 epilogue, merged rmsnorm launch, XOR swizzles (0 bank conflicts).
// ---------------------------------------------------------------------------

typedef __attribute__((ext_vector_type(8))) short bf16x8;   // 8 bf16 = 4 VGPRs
typedef __attribute__((ext_vector_type(4))) float f32x4;
typedef __attribute__((ext_vector_type(4))) unsigned short us4;

#if __has_builtin(__builtin_amdgcn_exp2f)
#define EXP2(x) __builtin_amdgcn_exp2f(x)
#else
#define EXP2(x) exp2f(x)
#endif

__device__ __forceinline__ unsigned short f2bf(float f) {
    unsigned int x = __float_as_uint(f);
    unsigned int r = x + 0x7fffu + ((x >> 16) & 1u);   // RN-even
    return (unsigned short)(r >> 16);
}
__device__ __forceinline__ unsigned short f2bf_fast(float f) {   // round-half-up
    return (unsigned short)((__float_as_uint(f) + 0x8000u) >> 16);
}
__device__ __forceinline__ float bf2f(unsigned short u) {
    return __uint_as_float(((unsigned int)u) << 16);
}

// async global->LDS, 16 B per lane; LDS dest = wave-uniform base + lane*16
__device__ __forceinline__ void gll16(const unsigned short* g, unsigned short* l) {
    __builtin_amdgcn_global_load_lds(
        (const __attribute__((address_space(1))) unsigned int*)g,
        (__attribute__((address_space(3))) unsigned int*)l, 16, 0, 0);
}

// ---------------------------------------------------------------------------
// elementwise fp32 -> bf16 (vectorized float4 -> ushort4)
// ---------------------------------------------------------------------------
__global__ __launch_bounds__(256) void cvt_bf16(const float* __restrict__ in,
                                                unsigned short* __restrict__ out) {
    int i = blockIdx.x * 256 + threadIdx.x;       // over n/4
    float4 v = ((const float4*)in)[i];
    us4 r;
    r[0] = f2bf(v.x); r[1] = f2bf(v.y); r[2] = f2bf(v.z); r[3] = f2bf(v.w);
    ((us4*)out)[i] = r;
}

// ---------------------------------------------------------------------------
// fp32 (R x C) -> bf16 transposed (C x R).  block (32,8), 32x32 LDS tile.
// ---------------------------------------------------------------------------
__global__ __launch_bounds__(256) void transpose_cvt(const float* __restrict__ in,
                                                     unsigned short* __restrict__ out,
                                                     int R, int C) {
    __shared__ float t[32][33];
    int c0 = blockIdx.x * 32, r0 = blockIdx.y * 32;
    int tx = threadIdx.x, ty = threadIdx.y;
#pragma unroll
    for (int i = 0; i < 4; i++)
        t[ty + i * 8][tx] = in[(size_t)(r0 + ty + i * 8) * C + c0 + tx];
    __syncthreads();
#pragma unroll
    for (int i = 0; i < 4; i++)
        out[(size_t)(c0 + ty + i * 8) * R + r0 + tx] = f2bf(t[tx][ty + i * 8]);
}

// ---------------------------------------------------------------------------
// shared GEMM mainloop: C[128m x 128n] += A(M,K) * Bt(N,K)^T, bf16, BK=64.
// 256 threads = 4 waves (2x2), each wave 64x64 = 4x4 frags of 16x16x32 MFMA.
// LDS rows (64 elems = 8 chunks of 16B) XOR-swizzled: chunk ^= row&7.
// R3 measured: 0 bank conflicts with this pattern.
// ---------------------------------------------------------------------------
__device__ __forceinline__ void gemm_core(const unsigned short* __restrict__ A,
                                          const unsigned short* __restrict__ Bt,
                                          int K, int rowA0, int colB0,
                                          unsigned short* As, unsigned short* Bs,
                                          f32x4 acc[4][4]) {
    const int tid = threadIdx.x;
    const int w = tid >> 6, lane = tid & 63;
    const int quad = lane >> 4, l15 = lane & 15;
    const int wm = w >> 1, wn = w & 1;
    const int lr = lane >> 3;                 // row within the 8-row chunk
    const int lc = ((lane & 7) ^ lr) * 8;     // swizzled element col within 64

    const unsigned short* ga[4]; const unsigned short* gb[4];
    unsigned short* la[4]; unsigned short* lb[4];
#pragma unroll
    for (int i = 0; i < 4; i++) {
        int r = w * 32 + i * 8;
        ga[i] = A  + (size_t)(rowA0 + r + lr) * K + lc;
        gb[i] = Bt + (size_t)(colB0 + r + lr) * K + lc;
        la[i] = As + r * 64;
        lb[i] = Bs + r * 64;
    }
    const int sw = (l15 & 7);                 // read-side swizzle key
    const int KT = K >> 6;
    for (int kt = 0; kt < KT; kt++) {
        const int ko = kt * 64;
#pragma unroll
        for (int i = 0; i < 4; i++) gll16(ga[i] + ko, la[i]);
#pragma unroll
        for (int i = 0; i < 4; i++) gll16(gb[i] + ko, lb[i]);
        __syncthreads();
#pragma unroll
        for (int kk = 0; kk < 2; kk++) {
            bf16x8 af[4], bfr[4];
#pragma unroll
            for (int mi = 0; mi < 4; mi++)
                af[mi] = *(const bf16x8*)&As[(wm * 64 + mi * 16 + l15) * 64 +
                                             (((kk * 4 + quad) ^ sw) * 8)];
#pragma unroll
            for (int ni = 0; ni < 4; ni++)
                bfr[ni] = *(const bf16x8*)&Bs[(wn * 64 + ni * 16 + l15) * 64 +
                                              (((kk * 4 + quad) ^ sw) * 8)];
#pragma unroll
            for (int mi = 0; mi < 4; mi++)
#pragma unroll
                for (int ni = 0; ni < 4; ni++)
                    acc[mi][ni] = __builtin_amdgcn_mfma_f32_16x16x32_bf16(
                        af[mi], bfr[ni], acc[mi][ni], 0, 0, 0);
        }
        __syncthreads();
    }
}

// ---------------------------------------------------------------------------
// GEMM1: proj = Xb @ Wqkvg.  Epilogue: q/k scatter -> (b,h,l,d); V written
// TRANSPOSED -> Vt (b,h,d,l) via LDS tile (fused transpose_v); gate -> sigmoid.
// ---------------------------------------------------------------------------
__global__ __launch_bounds__(256) void gemm_qkvg(const unsigned short* __restrict__ A,
                                                 const unsigned short* __restrict__ Bt,
                                                 unsigned short* __restrict__ Qb,
                                                 unsigned short* __restrict__ Kb,
                                                 unsigned short* __restrict__ Vt,
                                                 unsigned short* __restrict__ Gb) {
    __shared__ unsigned short smem[128 * 128];   // As|Bs in core, vtile in epilogue
    unsigned short* As = smem;
    unsigned short* Bs = smem + 128 * 64;
    f32x4 acc[4][4];
    f32x4 z = {0.f, 0.f, 0.f, 0.f};
#pragma unroll
    for (int i = 0; i < 4; i++)
#pragma unroll
        for (int j = 0; j < 4; j++) acc[i][j] = z;

    const int rowA0 = blockIdx.y * 128, colB0 = blockIdx.x * 128;
    gemm_core(A, Bt, 2048, rowA0, colB0, As, Bs, acc);

    const int tid = threadIdx.x, w = tid >> 6, lane = tid & 63;
    const int quad = lane >> 4, l15 = lane & 15;
    const int wm = w >> 1, wn = w & 1;
    const int sec = blockIdx.x >> 4;     // 0=q 1=k 2=v 3=gate
    const int h = blockIdx.x & 15;

    if (sec == 2) {
        // V: acc -> LDS as (d, l) tile, 16B-chunk swizzled (chunk ^= d&15)
        __syncthreads();
#pragma unroll
        for (int mi = 0; mi < 4; mi++)
#pragma unroll
            for (int ni = 0; ni < 4; ni++)
#pragma unroll
                for (int i = 0; i < 4; i++) {
                    int ll = wm * 64 + mi * 16 + quad * 4 + i;   // l within tile
                    int d  = wn * 64 + ni * 16 + l15;
                    smem[d * 128 + (((ll >> 3) ^ (d & 15)) * 8) + (ll & 7)] =
                        f2bf(acc[mi][ni][i]);
                }
        __syncthreads();
        const int b_ = rowA0 >> 11, l0 = rowA0 & 2047;
        const int r = tid >> 1, hf = tid & 1;    // r = d row, hf = 64-col half
        unsigned short* drow = Vt + (size_t)(b_ * 16 + h) * 128 * 2048 +
                               (size_t)r * 2048 + l0;
#pragma unroll
        for (int jj = 0; jj < 8; jj++) {
            int jcol = hf * 8 + jj;
            *(bf16x8*)(drow + jcol * 8) =
                *(const bf16x8*)&smem[r * 128 + ((jcol ^ (r & 15)) * 8)];
        }
    } else if (sec == 3) {
#pragma unroll
        for (int mi = 0; mi < 4; mi++)
#pragma unroll
            for (int ni = 0; ni < 4; ni++)
#pragma unroll
                for (int i = 0; i < 4; i++) {
                    int rowg = rowA0 + wm * 64 + mi * 16 + quad * 4 + i;  // b*L+l
                    int d = wn * 64 + ni * 16 + l15;
                    float g = 1.f / (1.f + __expf(-acc[mi][ni][i]));
                    Gb[((size_t)rowg << 11) + h * 128 + d] = f2bf(g);
                }
    } else {
        unsigned short* dst = (sec == 0) ? Qb : Kb;
#pragma unroll
        for (int mi = 0; mi < 4; mi++)
#pragma unroll
            for (int ni = 0; ni < 4; ni++)
#pragma unroll
                for (int i = 0; i < 4; i++) {
                    int rowg = rowA0 + wm * 64 + mi * 16 + quad * 4 + i;
                    int d = wn * 64 + ni * 16 + l15;
                    int b_ = rowg >> 11, l_ = rowg & 2047;
                    dst[(((size_t)(b_ * 16 + h) * 2048 + l_) << 7) + d] =
                        f2bf(acc[mi][ni][i]);
                }
    }
}

// ---------------------------------------------------------------------------
// GEMM2: out = OG @ Wout  (fp32 epilogue straight to d_out)
// ---------------------------------------------------------------------------
__global__ __launch_bounds__(256) void gemm_out(const unsigned short* __restrict__ A,
                                                const unsigned short* __restrict__ Bt,
                                                float* __restrict__ C) {
    __shared__ unsigned short As[128 * 64], Bs[128 * 64];
    f32x4 acc[4][4];
    f32x4 z = {0.f, 0.f, 0.f, 0.f};
#pragma unroll
    for (int i = 0; i < 4; i++)
#pragma unroll
        for (int j = 0; j < 4; j++) acc[i][j] = z;

    const int rowA0 = blockIdx.y * 128, colB0 = blockIdx.x * 128;
    gemm_core(A, Bt, 2048, rowA0, colB0, As, Bs, acc);

    const int tid = threadIdx.x, w = tid >> 6, lane = tid & 63;
    const int quad = lane >> 4, l15 = lane & 15;
    const int wm = w >> 1, wn = w & 1;
#pragma unroll
    for (int mi = 0; mi < 4; mi++)
#pragma unroll
        for (int ni = 0; ni < 4; ni++)
#pragma unroll
            for (int i = 0; i < 4; i++) {
                int rowg = rowA0 + wm * 64 + mi * 16 + quad * 4 + i;
                int col = colB0 + wn * 64 + ni * 16 + l15;
                C[(size_t)rowg * 2048 + col] = acc[mi][ni][i];
            }
}

// ---------------------------------------------------------------------------
// RMSNorm + RoPE in place on Q and K (each (64, 2048, 128) bf16), one launch.
// blockIdx.y picks the tensor; one wave per row.
// ---------------------------------------------------------------------------
__global__ __launch_bounds__(256) void rmsnorm_rope(unsigned short* __restrict__ Qp,
                                                    unsigned short* __restrict__ Kp) {
    unsigned short* X = blockIdx.y ? Kp : Qp;
    const int tid = threadIdx.x;
    const int row = blockIdx.x * 4 + (tid >> 6);
    const int lane = tid & 63;
    unsigned short* p = X + (size_t)row * 128;
    const int l_ = row & 2047;                      // sequence position
    float x1 = bf2f(p[lane]);
    float x2 = bf2f(p[lane + 64]);
    float ss = x1 * x1 + x2 * x2;
#pragma unroll
    for (int off = 32; off >= 1; off >>= 1) ss += __shfl_xor(ss, off, 64);
    float r = rsqrtf(ss * (1.f / 128.f) + 1e-5f);
    x1 *= r; x2 *= r;
    float inv = exp2f(-(float)lane * (13.287712379549449f / 64.f));
    float ang = (float)l_ * inv;
    float sn, cs;
    sincosf(ang, &sn, &cs);
    p[lane]      = f2bf(x1 * cs - x2 * sn);
    p[lane + 64] = f2bf(x1 * sn + x2 * cs);
}

// ---------------------------------------------------------------------------
// Flash attention (causal) + gate fusion, no-max softmax.
// grid 512 blocks, 512 threads = 8 waves; q-tile 256 (wave w owns q rows
// [w*32, w*32+32)); KV tile 64, PV in two 32-kv halves so Ps is 16 KB.
// LDS: Ks 16K + Vs 16K + Ps 16K = 48 KB.  Plain launch_bounds: compiler
// picks ~84 VGPR (R3) -> up to 3 blocks/CU without spilling; forcing 6
// waves/EU (R4) spilled the accumulators (2 GB scratch traffic).
// Block mapping groups all 8 q-chunks of a head on one XCD.
// P is wave-local: no barrier between P write and PV read.
// ---------------------------------------------------------------------------
__global__ __launch_bounds__(512) void fa_kernel(const unsigned short* __restrict__ Q,
                                                 const unsigned short* __restrict__ K,
                                                 const unsigned short* __restrict__ Vt,
                                                 const unsigned short* __restrict__ G,
                                                 unsigned short* __restrict__ Og) {
    __shared__ unsigned short Ks[64 * 128];     // (kv, d)
    __shared__ unsigned short Vs[128 * 64];     // (d, kv)
    __shared__ unsigned short Ps[256 * 32];     // (q, kv-half) wave-local slabs
    const int g = blockIdx.x;
    const int bh = (g & 7) | ((g >> 6) << 3);   // all qc of a head share g%8
    const int qc = (g >> 3) & 7;                // q-chunk 0..7 (256 rows each)
    const int tid = threadIdx.x, w = tid >> 6, lane = tid & 63;
    const int quad = lane >> 4, l15 = lane & 15;
    const int sw = l15 & 7;
    const int qrow0 = qc * 256 + w * 32;        // global q row base for this wave
    const float CS = 0.12751740395609812f;      // (1/sqrt(128)) * log2(e)

    // Q fragments (A-operand layout), loaded once
    bf16x8 qf[2][4];
#pragma unroll
    for (int mi = 0; mi < 2; mi++)
#pragma unroll
        for (int kt = 0; kt < 4; kt++)
            qf[mi][kt] = *(const bf16x8*)(Q + ((size_t)bh * 2048 + qrow0 + mi * 16 + l15) * 128
                                             + kt * 32 + quad * 8);

    f32x4 o[2][8];
    f32x4 z = {0.f, 0.f, 0.f, 0.f};
#pragma unroll
    for (int mi = 0; mi < 2; mi++)
#pragma unroll
        for (int nj = 0; nj < 8; nj++) o[mi][nj] = z;
    float rowsum[2][4];
#pragma unroll
    for (int mi = 0; mi < 2; mi++)
#pragma unroll
        for (int i = 0; i < 4; i++) rowsum[mi][i] = 0.f;

    const unsigned short* Kbase = K + (size_t)bh * 2048 * 128;
    const unsigned short* Vtb   = Vt + (size_t)bh * 128 * 2048;

    // Ps a-frag read offsets (row-dependent swizzle key = (row>>1)&3)
    const int pr0 = w * 32 + l15, pr1 = pr0 + 16;
    const int pk0 = (pr0 >> 1) & 3, pk1 = (pr1 >> 1) & 3;

    const int NJ = 4 * (qc + 1);    // kv tiles of 64
    for (int j = 0; j < NJ; j++) {
        __syncthreads();   // prev iter's Ks/Vs reads complete

        // --- stage K tile: 64 rows x 256 B; wave w -> rows [w*8, w*8+8) ---
        {
            const int rowoff = lane >> 4, c = lane & 15;
#pragma unroll
            for (int i = 0; i < 2; i++) {
                int r0 = w * 8 + i * 4;
                int row = r0 + rowoff;
                int cs_ = (c & 8) | ((c & 7) ^ (row & 7));
                gll16(Kbase + (size_t)(j * 64 + row) * 128 + cs_ * 8, Ks + r0 * 128);
            }
        }
        // --- stage V tile: 128 d-rows x 128 B; wave w -> rows [w*16, w*16+16) ---
        {
            const int rowoff = lane >> 3, c = lane & 7;
#pragma unroll
            for (int i = 0; i < 2; i++) {
                int r0 = w * 16 + i * 8;
                int row = r0 + rowoff;
                gll16(Vtb + (size_t)row * 2048 + j * 64 + ((c ^ (row & 7)) * 8),
                      Vs + r0 * 64);
            }
        }
        __syncthreads();   // staged data visible

        if (j * 64 >= qrow0 + 32) continue;   // tile fully masked for this wave

        // --- S = Q K^T (raw logits) ---
        f32x4 s[2][4];
#pragma unroll
        for (int mi = 0; mi < 2; mi++)
#pragma unroll
            for (int nj = 0; nj < 4; nj++) s[mi][nj] = z;
#pragma unroll
        for (int kt = 0; kt < 4; kt++)
#pragma unroll
            for (int nj = 0; nj < 4; nj++) {
                bf16x8 bfr = *(const bf16x8*)&Ks[(nj * 16 + l15) * 128 +
                                                 (((kt * 4 + quad) ^ sw) * 8)];
                s[0][nj] = __builtin_amdgcn_mfma_f32_16x16x32_bf16(qf[0][kt], bfr, s[0][nj], 0, 0, 0);
                s[1][nj] = __builtin_amdgcn_mfma_f32_16x16x32_bf16(qf[1][kt], bfr, s[1][nj], 0, 0, 0);
            }

        // --- two 32-kv halves: exp + P write + PV MFMA (Ps wave-local) ---
        const bool diag = (j * 64 + 63 > qrow0);   // any masking in this tile?
#pragma unroll
        for (int hh = 0; hh < 2; hh++) {
#pragma unroll
            for (int mi = 0; mi < 2; mi++)
#pragma unroll
                for (int njh = 0; njh < 2; njh++) {
                    const int nj = hh * 2 + njh;
#pragma unroll
                    for (int i = 0; i < 4; i++) {
                        float pp = EXP2(s[mi][nj][i] * CS);
                        int row_l = mi * 16 + quad * 4 + i;      // 0..31 in slab
                        if (diag) {
                            int col_g = j * 64 + nj * 16 + l15;
                            if (col_g > qrow0 + row_l) pp = 0.f;
                        }
                        rowsum[mi][i] += pp;
                        int row = w * 32 + row_l;
                        int kv = njh * 16 + l15;                 // 0..31
                        Ps[row * 32 + ((((kv >> 3) ^ ((row >> 1) & 3)) * 8)) + (kv & 7)] =
                            f2bf_fast(pp);
                    }
                }
            // PV for this half (K=32 -> one MFMA pair per o-column)
            bf16x8 a0 = *(const bf16x8*)&Ps[pr0 * 32 + ((quad ^ pk0) * 8)];
            bf16x8 a1 = *(const bf16x8*)&Ps[pr1 * 32 + ((quad ^ pk1) * 8)];
#pragma unroll
            for (int nj = 0; nj < 8; nj++) {
                bf16x8 bfr = *(const bf16x8*)&Vs[(nj * 16 + l15) * 64 +
                                                 (((hh * 4 + quad) ^ sw) * 8)];
                o[0][nj] = __builtin_amdgcn_mfma_f32_16x16x32_bf16(a0, bfr, o[0][nj], 0, 0, 0);
                o[1][nj] = __builtin_amdgcn_mfma_f32_16x16x32_bf16(a1, bfr, o[1][nj], 0, 0, 0);
            }
        }
    }

    // --- epilogue: reduce rowsum across l15 lanes, O/l * gate -> Og ---
    const int b_ = bh >> 4, h = bh & 15;
#pragma unroll
    for (int mi = 0; mi < 2; mi++)
#pragma unroll
        for (int i = 0; i < 4; i++) {
            float t = rowsum[mi][i];
#pragma unroll
            for (int off = 1; off < 16; off <<= 1) t += __shfl_xor(t, off, 16);
            float rl = 1.f / t;
            int l_ = qrow0 + mi * 16 + quad * 4 + i;
#pragma unroll
            for (int nj = 0; nj < 8; nj++) {
                int d = nj * 16 + l15;
                size_t gi = ((size_t)(b_ * 2048 + l_) * 2048) + h * 128 + d;
                Og[gi] = f2bf(o[mi][nj][i] * rl * bf2f(G[gi]));
            }
        }
}

// ---------------------------------------------------------------------------
// launch
// ---------------------------------------------------------------------------
extern "C" void kernel_launch(void* const* d_in, const int* in_sizes, int n_in,
                              void* d_out, int out_size, void* d_ws, size_t ws_size,
                              hipStream_t stream) {
    const float* X  = (const float*)d_in[0];   // (4,2048,2048)
    const float* Wq = (const float*)d_in[1];   // (2048,8192)
    const float* Wo = (const float*)d_in[2];   // (2048,2048)
    float* out = (float*)d_out;                // (4,2048,2048) fp32

    char* ws = (char*)d_ws;
    const size_t SZ = 33554432ull;             // 16.8M bf16
    unsigned short* Xb  = (unsigned short*)(ws);                 // X bf16 / later OG
    unsigned short* Wqt = (unsigned short*)(ws + SZ);            // Wqkvg^T
    unsigned short* Wot = (unsigned short*)(ws + 2 * SZ);        // 8.4 MB
    unsigned short* Qb  = (unsigned short*)(ws + 2 * SZ + 8388608ull);
    unsigned short* Kb  = (unsigned short*)(ws + 3 * SZ + 8388608ull);
    unsigned short* Vt  = (unsigned short*)(ws + 4 * SZ + 8388608ull);  // (bh,d,l)
    unsigned short* Gb  = (unsigned short*)(ws + 5 * SZ + 8388608ull);
    unsigned short* OG  = Xb;    // reuse: Xb dead after GEMM1

    cvt_bf16<<<16384, 256, 0, stream>>>(X, Xb);
    transpose_cvt<<<dim3(256, 64), dim3(32, 8), 0, stream>>>(Wq, Wqt, 2048, 8192);
    transpose_cvt<<<dim3(64, 64),  dim3(32, 8), 0, stream>>>(Wo, Wot, 2048, 2048);

    gemm_qkvg<<<dim3(64, 64), 256, 0, stream>>>(Xb, Wqt, Qb, Kb, Vt, Gb);

    rmsnorm_rope<<<dim3(32768, 2), 256, 0, stream>>>(Qb, Kb);

    fa_kernel<<<512, 512, 0, stream>>>(Qb, Kb, Vt, Gb, OG);

    gemm_out<<<dim3(16, 64), 256, 0, stream>>>(OG, Wot, out);
}